// Round 17
// baseline (42.943 us; speedup 1.0000x reference)
//
#include <hip/hip_runtime.h>

#define BB 8
#define SS 2048
#define HH 128
#define NHH 4
#define DHH 32

typedef _Float16 f16;
typedef f16 f16x4 __attribute__((ext_vector_type(4)));
typedef f16 f16x8 __attribute__((ext_vector_type(8)));
typedef float f32x4 __attribute__((ext_vector_type(4)));

__device__ __forceinline__ f16x8 cat(f16x4 a, f16x4 b) {
  return (f16x8){a[0], a[1], a[2], a[3], b[0], b[1], b[2], b[3]};
}

// hardware transpose read (R2/R3/R5-proven): on a contiguous [16 rows][16 cols]
// f16 panel, tr_read(panel + lane*4) gives lane(lg,lm) elem j = panel[4*lg+j][lm].
// CALLER MUST wait lgkmcnt(0) + sched_barrier(0) before use (rule #18).
__device__ __forceinline__ f16x4 tr_read(const f16* p) {
  f16x4 d;
  asm volatile("ds_read_b64_tr_b16 %0, %1"
               : "=v"(d)
               : "v"((__attribute__((address_space(3))) const f16*)p)
               : "memory");
  return d;
}

// ---- stage1: LN1 (blocks 0..1023) + weights->f16 (1024..1055) + mask scan (1056..1063)
__global__ __launch_bounds__(256) void stage1_kernel(const float* __restrict__ x,
                                                     const float* __restrict__ ga,
                                                     const float* __restrict__ gb,
                                                     const float* __restrict__ Wl,
                                                     const float* __restrict__ W1,
                                                     const int* __restrict__ mask,
                                                     f16* __restrict__ n1,
                                                     f16* __restrict__ Wlf,
                                                     f16* __restrict__ W1f,
                                                     int* __restrict__ idx,
                                                     int* __restrict__ nkcnt,
                                                     int* __restrict__ nkpad) {
  const int tid = threadIdx.x;
  if (blockIdx.x < 1024) {  // ---- LayerNorm path: 16 rows/block
    const int wave = tid >> 6, lane = tid & 63;
    const int grp = lane >> 4, lm = lane & 15;
    const int r = wave * 4 + grp;
    const size_t row = (size_t)blockIdx.x * 16 + r;

    const float* xr = x + row * HH + lm * 8;
    float4 v0 = *(const float4*)(xr);
    float4 v1 = *(const float4*)(xr + 4);
    float xv[8] = {v0.x, v0.y, v0.z, v0.w, v1.x, v1.y, v1.z, v1.w};
    float sum = 0.f, sq = 0.f;
#pragma unroll
    for (int j = 0; j < 8; ++j) { sum += xv[j]; sq += xv[j] * xv[j]; }
#pragma unroll
    for (int m = 1; m < 16; m <<= 1) {
      sum += __shfl_xor(sum, m);
      sq += __shfl_xor(sq, m);
    }
    float mean = sum * (1.0f / HH);
    float var = fmaxf((sq - (float)HH * mean * mean) * (1.0f / (HH - 1)), 0.0f);
    float inv = 1.0f / (sqrtf(var) + 1e-6f);

    float4 a0 = *(const float4*)(ga + lm * 8);
    float4 a1 = *(const float4*)(ga + lm * 8 + 4);
    float4 b0 = *(const float4*)(gb + lm * 8);
    float4 b1 = *(const float4*)(gb + lm * 8 + 4);
    float av[8] = {a0.x, a0.y, a0.z, a0.w, a1.x, a1.y, a1.z, a1.w};
    float bv[8] = {b0.x, b0.y, b0.z, b0.w, b1.x, b1.y, b1.z, b1.w};
    f16x8 w;
#pragma unroll
    for (int j = 0; j < 8; ++j) w[j] = (f16)(av[j] * (xv[j] - mean) * inv + bv[j]);
    *(f16x8*)(n1 + row * HH + lm * 8) = w;
    return;
  }
  if (blockIdx.x < 1056) {  // ---- weight conversion path
    int g = (blockIdx.x - 1024) * 256 + tid;
    if (g < 4096) {
      float4 w = ((const float4*)Wl)[g];
      f16x4 o = {(f16)w.x, (f16)w.y, (f16)w.z, (f16)w.w};
      ((f16x4*)Wlf)[g] = o;
    } else {
      float4 w = ((const float4*)W1)[g - 4096];
      f16x4 o = {(f16)w.x, (f16)w.y, (f16)w.z, (f16)w.w};
      ((f16x4*)W1f)[g - 4096] = o;
    }
    return;
  }
  // ---- mask scan path: one block per batch
  const int b = blockIdx.x - 1056;
  __shared__ int ps[256];
  int m8[8];
  int cnt = 0;
  const int* mp = mask + b * SS + tid * 8;
#pragma unroll
  for (int j = 0; j < 8; ++j) {
    m8[j] = mp[j];
    cnt += (m8[j] != 0);
  }
  ps[tid] = cnt;
  __syncthreads();
  for (int off = 1; off < 256; off <<= 1) {
    int v = (tid >= off) ? ps[tid - off] : 0;
    __syncthreads();
    ps[tid] += v;
    __syncthreads();
  }
  int pos = ps[tid] - cnt;  // exclusive prefix
#pragma unroll
  for (int j = 0; j < 8; ++j) {
    if (m8[j] != 0) idx[b * SS + pos++] = tid * 8 + j;
  }
  __syncthreads();
  int nkv = ps[255];
  int npv = (nkv + 63) & ~63;
  if (npv == 0) npv = 64;
  for (int jj = nkv + tid; jj < npv; jj += 256) idx[b * SS + jj] = 0;  // safe pad rows
  if (tid == 255) { nkcnt[b] = nkv; nkpad[b] = npv; }
}

// ---- attention: R15 structure (zero main-loop barriers, wave-private dbuf
// tiles, XCD swizzle) + BLOCK-LEVEL KEY-SPLIT (ks=0/1 handles half the chunks).
// Each split writes self-normalized partial output (f16) + its denominator.
// grid = 2 * B*NH*(S/128) = 1024; 4 waves; wave = 32 q; chunk = 64 keys
__global__ __launch_bounds__(256, 4) void attn_kernel(const f16* __restrict__ n1,
                                                      const int* __restrict__ idx,
                                                      const int* __restrict__ nkcnt,
                                                      const int* __restrict__ nkpad,
                                                      const float* __restrict__ scalew,
                                                      f16* __restrict__ pnum,
                                                      float* __restrict__ pden) {
  const int tid = threadIdx.x;
  const int b = blockIdx.x & 7;          // XCD-aligned batch (8 batches <-> 8 XCDs)
  const int qb = (blockIdx.x >> 3) & 15;
  const int h = (blockIdx.x >> 7) & 3;
  const int ks = blockIdx.x >> 9;        // key-split half 0/1
  const int wave = tid >> 6, lane = tid & 63;
  const int lg = lane >> 4, lm = lane & 15;
  const int nk = nkcnt[b];
  const int ns = nkpad[b] >> 6;
  const int hc = (ns + 1) >> 1;
  const int c0 = ks * hc;
  const int c1 = (c0 + hc < ns) ? c0 + hc : ns;

  __shared__ __align__(16) f16 Kt[4][2][2048];  // [wave][buf][dg*1024+key*16+d] 32KB
  __shared__ __align__(16) int idxL[SS];        // 8KB

  const f16* __restrict__ nb = n1 + (size_t)b * SS * HH + h * DHH;
  f16* __restrict__ tile = &Kt[wave][0][0];

  for (int j = tid * 4; j < (ns << 6); j += 1024)
    *(int4*)&idxL[j] = *(const int4*)(idx + b * SS + j);

  const int q0 = qb * 128 + wave * 32 + lm;
  f16x8 qf[2];
#pragma unroll
  for (int qt = 0; qt < 2; ++qt) {
    int q = q0 + qt * 16;
    f16x8 raw = *(const f16x8*)(nb + (size_t)q * HH + lg * 8);
    f16 s = (f16)(scalew[h * SS + q] * 0.2550680718664f);  // (1/sqrt32)*log2e
#pragma unroll
    for (int j = 0; j < 8; ++j) raw[j] *= s;  // fold scale into Q; bias cancels
    qf[qt] = raw;
  }

  const int sk = lane >> 2, sp = lane & 3;  // 4 lanes per key: 64B contiguous slices

  const f32x4 zero = {0.f, 0.f, 0.f, 0.f};
  f32x4 acc[2][2] = {{zero, zero}, {zero, zero}};  // [qt][dh]
  f32x4 lacc[2] = {zero, zero};
  const f16x8 ones = {(f16)1, (f16)1, (f16)1, (f16)1, (f16)1, (f16)1, (f16)1, (f16)1};

  __syncthreads();  // idxL ready — the only barrier

  if (c0 < c1) {  // prologue: stage chunk c0 into buf (c0&1)
#pragma unroll
    for (int i = 0; i < 4; ++i) {
      int row = idxL[c0 * 64 + i * 16 + sk];
      f16x8 v = *(const f16x8*)(nb + (size_t)row * HH + sp * 8);
      *(f16x8*)(tile + (c0 & 1) * 2048 + (sp >> 1) * 1024 + (i * 16 + sk) * 16 + (sp & 1) * 8) = v;
    }
  }

  for (int c = c0; c < c1; ++c) {
    const int bo = (c & 1) * 2048;   // current buffer offset (f16 units)
    const int k0 = c * 64;
    f16x8 kreg[4];
    const bool more = (c + 1 < c1);
    if (more) {  // issue next chunk's gather early (consumed at loop bottom)
#pragma unroll
      for (int i = 0; i < 4; ++i) {
        int row = idxL[k0 + 64 + i * 16 + sk];
        kreg[i] = *(const f16x8*)(nb + (size_t)row * HH + sp * 8);
      }
    }

    // V^T fragments first (tr before kf: in-order DS => kf waits cover tr)
    f16x4 t0a = tr_read(tile + bo + 0 + lane * 4);     // dg0 keys 0-15
    f16x4 t0b = tr_read(tile + bo + 256 + lane * 4);   // dg0 keys 16-31
    f16x4 t0c = tr_read(tile + bo + 512 + lane * 4);
    f16x4 t0d = tr_read(tile + bo + 768 + lane * 4);
    f16x4 t1a = tr_read(tile + bo + 1024 + lane * 4);  // dg1
    f16x4 t1b = tr_read(tile + bo + 1280 + lane * 4);
    f16x4 t1c = tr_read(tile + bo + 1536 + lane * 4);
    f16x4 t1d = tr_read(tile + bo + 1792 + lane * 4);

    f16x8 kf[4];
#pragma unroll
    for (int t = 0; t < 4; ++t)
      kf[t] = *(const f16x8*)(tile + bo + (lg >> 1) * 1024 + (t * 16 + lm) * 16 + (lg & 1) * 8);

    const bool tail = (k0 + 64 > nk);
    f16x8 pf[2][2];
#define PF_LOOP(MASKED)                                                                   \
  _Pragma("unroll") for (int qt = 0; qt < 2; ++qt) {                                      \
    _Pragma("unroll") for (int t = 0; t < 4; ++t) {                                       \
      f32x4 st = __builtin_amdgcn_mfma_f32_16x16x32_f16(kf[t], qf[qt], zero, 0, 0, 0);    \
      _Pragma("unroll") for (int r = 0; r < 4; ++r) {                                     \
        float pe = __builtin_amdgcn_exp2f(st[r]);                                         \
        if (MASKED && (k0 + t * 16 + lg * 4 + r >= nk)) pe = 0.0f;                        \
        pf[qt][t >> 1][(t & 1) * 4 + r] = (f16)pe;                                        \
      }                                                                                   \
    }                                                                                     \
  }
    if (!tail) { PF_LOOP(false) } else { PF_LOOP(true) }
#undef PF_LOOP

    // denominator on matrix pipe
#pragma unroll
    for (int qt = 0; qt < 2; ++qt) {
#pragma unroll
      for (int s = 0; s < 2; ++s)
        lacc[qt] = __builtin_amdgcn_mfma_f32_16x16x32_f16(ones, pf[qt][s], lacc[qt], 0, 0, 0);
    }

    asm volatile("s_waitcnt lgkmcnt(0)" ::: "memory");
    __builtin_amdgcn_sched_barrier(0);

    f16x8 vf;
    vf = cat(t0a, t0b);  // dh0, keys 0-31
#pragma unroll
    for (int qt = 0; qt < 2; ++qt)
      acc[qt][0] = __builtin_amdgcn_mfma_f32_16x16x32_f16(vf, pf[qt][0], acc[qt][0], 0, 0, 0);
    vf = cat(t1a, t1b);  // dh1, keys 0-31
#pragma unroll
    for (int qt = 0; qt < 2; ++qt)
      acc[qt][1] = __builtin_amdgcn_mfma_f32_16x16x32_f16(vf, pf[qt][0], acc[qt][1], 0, 0, 0);
    vf = cat(t0c, t0d);  // dh0, keys 32-63
#pragma unroll
    for (int qt = 0; qt < 2; ++qt)
      acc[qt][0] = __builtin_amdgcn_mfma_f32_16x16x32_f16(vf, pf[qt][1], acc[qt][0], 0, 0, 0);
    vf = cat(t1c, t1d);  // dh1, keys 32-63
#pragma unroll
    for (int qt = 0; qt < 2; ++qt)
      acc[qt][1] = __builtin_amdgcn_mfma_f32_16x16x32_f16(vf, pf[qt][1], acc[qt][1], 0, 0, 0);

    if (more) {  // stage chunk c+1 into other buffer (own tile; in-order DS = safe)
      const int bn = 2048 - (c & 1) * 2048;
#pragma unroll
      for (int i = 0; i < 4; ++i)
        *(f16x8*)(tile + bn + (sp >> 1) * 1024 + (i * 16 + sk) * 16 + (sp & 1) * 8) = kreg[i];
    }
  }

  // epilogue: self-normalized partial (f16) + denominator (f32)
#pragma unroll
  for (int qt = 0; qt < 2; ++qt) {
    float den = lacc[qt][0];
    float inv = (den > 0.f) ? 1.0f / den : 0.f;
    int q = q0 + qt * 16;
    size_t row = (size_t)ks * BB * SS + (size_t)b * SS + q;
    f16* op = pnum + row * HH + h * DHH;
    f16x4 o0 = {(f16)(acc[qt][0][0] * inv), (f16)(acc[qt][0][1] * inv),
                (f16)(acc[qt][0][2] * inv), (f16)(acc[qt][0][3] * inv)};
    f16x4 o1 = {(f16)(acc[qt][1][0] * inv), (f16)(acc[qt][1][1] * inv),
                (f16)(acc[qt][1][2] * inv), (f16)(acc[qt][1][3] * inv)};
    *(f16x4*)(op + lg * 4) = o0;
    *(f16x4*)(op + 16 + lg * 4) = o1;
    if (lg == 0) pden[row] = den;
  }
}

// ---- combine: out = (d0*o0 + d1*o1) / (d0+d1); grid 1024, 16 rows/block ----
__global__ __launch_bounds__(256) void combine_kernel(const f16* __restrict__ pnum,
                                                      const float* __restrict__ pden,
                                                      f16* __restrict__ hatt) {
  const int blk = blockIdx.x;
  const int b = blk & 7;  // XCD-aligned
  const int r0 = (blk >> 3) * 16;
  const int tid = threadIdx.x;
  const size_t row = (size_t)b * SS + r0 + (tid >> 4);
  const int cg = (tid & 15) * 8;
  float d0 = pden[row], d1 = pden[(size_t)BB * SS + row];
  float inv = 1.0f / (d0 + d1);
  float w0 = d0 * inv, w1 = d1 * inv;
  f16x8 a = *(const f16x8*)(pnum + row * HH + cg);
  f16x8 c = *(const f16x8*)(pnum + ((size_t)BB * SS + row) * HH + cg);
  f16x8 o;
#pragma unroll
  for (int j = 0; j < 8; ++j) o[j] = (f16)(w0 * (float)a[j] + w1 * (float)c[j]);
  *(f16x8*)(hatt + row * HH + cg) = o;
}

// ------- fused MLP: 32 rows/block, 256 thr (4 waves x 32 cols) ---------------
__global__ __launch_bounds__(256) void mlp_kernel(const f16* __restrict__ X,
                                                  const f16* __restrict__ Wlf,
                                                  const float* __restrict__ bl,
                                                  const float* __restrict__ resid,
                                                  const float* __restrict__ ln2a,
                                                  const float* __restrict__ ln2b,
                                                  const f16* __restrict__ W1f,
                                                  const float* __restrict__ b1,
                                                  const float* __restrict__ fscale,
                                                  float* __restrict__ out) {
  const int tid = threadIdx.x;
  const int wave = tid >> 6, lane = tid & 63;
  const int lg = lane >> 4, lm = lane & 15;
  const int rbase = blockIdx.x * 32;
  const int nc0 = wave * 32;

  __shared__ __align__(16) f16 n2t[32][136];
  __shared__ float red[4][32][2];

  f32x4 acc[2][2] = {};
  const f16* xr0 = X + (size_t)(rbase + lm) * HH;
  const f16* xr1 = X + (size_t)(rbase + 16 + lm) * HH;
#pragma unroll
  for (int ks = 0; ks < 4; ++ks) {
    f16x8 bf0 = *(const f16x8*)(xr0 + ks * 32 + lg * 8);
    f16x8 bf1 = *(const f16x8*)(xr1 + ks * 32 + lg * 8);
#pragma unroll
    for (int nt = 0; nt < 2; ++nt) {
      f16x8 af = *(const f16x8*)(Wlf + (size_t)(nc0 + nt * 16 + lm) * HH + ks * 32 + lg * 8);
      acc[0][nt] = __builtin_amdgcn_mfma_f32_16x16x32_f16(af, bf0, acc[0][nt], 0, 0, 0);
      acc[1][nt] = __builtin_amdgcn_mfma_f32_16x16x32_f16(af, bf1, acc[1][nt], 0, 0, 0);
    }
  }
  float sum[2] = {0.f, 0.f}, sq[2] = {0.f, 0.f};
  f32x4 o[2][2];
#pragma unroll
  for (int g = 0; g < 2; ++g) {
    int row = rbase + g * 16 + lm;
#pragma unroll
    for (int nt = 0; nt < 2; ++nt) {
      int n = nc0 + nt * 16 + lg * 4;
      float4 rv = *(const float4*)(resid + (size_t)row * HH + n);
      float4 bv = *(const float4*)(bl + n);
      f32x4 v = acc[g][nt];
      v[0] += rv.x + bv.x; v[1] += rv.y + bv.y;
      v[2] += rv.z + bv.z; v[3] += rv.w + bv.w;
      o[g][nt] = v;
      sum[g] += v[0] + v[1] + v[2] + v[3];
      sq[g] += v[0] * v[0] + v[1] * v[1] + v[2] * v[2] + v[3] * v[3];
    }
    sum[g] += __shfl_xor(sum[g], 16); sum[g] += __shfl_xor(sum[g], 32);
    sq[g] += __shfl_xor(sq[g], 16);  sq[g] += __shfl_xor(sq[g], 32);
  }
  if (lane < 16) {
#pragma unroll
    for (int g = 0; g < 2; ++g) {
      red[wave][g * 16 + lm][0] = sum[g];
      red[wave][g * 16 + lm][1] = sq[g];
    }
  }
  __syncthreads();
#pragma unroll
  for (int g = 0; g < 2; ++g) {
    int lr = g * 16 + lm;
    float ts = red[0][lr][0] + red[1][lr][0] + red[2][lr][0] + red[3][lr][0];
    float tq = red[0][lr][1] + red[1][lr][1] + red[2][lr][1] + red[3][lr][1];
    float mean = ts * (1.0f / HH);
    float var = fmaxf((tq - (float)HH * mean * mean) * (1.0f / (HH - 1)), 0.0f);
    float inv = 1.0f / (sqrtf(var) + 1e-6f);
#pragma unroll
    for (int nt = 0; nt < 2; ++nt) {
      int n = nc0 + nt * 16 + lg * 4;
      float4 av = *(const float4*)(ln2a + n);
      float4 b2 = *(const float4*)(ln2b + n);
      f16x4 w;
      w[0] = (f16)(av.x * (o[g][nt][0] - mean) * inv + b2.x);
      w[1] = (f16)(av.y * (o[g][nt][1] - mean) * inv + b2.y);
      w[2] = (f16)(av.z * (o[g][nt][2] - mean) * inv + b2.z);
      w[3] = (f16)(av.w * (o[g][nt][3] - mean) * inv + b2.w);
      *(f16x4*)(&n2t[lr][n]) = w;
    }
  }
  __syncthreads();

  f32x4 fa[2][2] = {};
#pragma unroll
  for (int ks = 0; ks < 4; ++ks) {
    f16x8 bf0 = *(const f16x8*)(&n2t[lm][ks * 32 + lg * 8]);
    f16x8 bf1 = *(const f16x8*)(&n2t[16 + lm][ks * 32 + lg * 8]);
#pragma unroll
    for (int nt = 0; nt < 2; ++nt) {
      f16x8 af = *(const f16x8*)(W1f + (size_t)(nc0 + nt * 16 + lm) * HH + ks * 32 + lg * 8);
      fa[0][nt] = __builtin_amdgcn_mfma_f32_16x16x32_f16(af, bf0, fa[0][nt], 0, 0, 0);
      fa[1][nt] = __builtin_amdgcn_mfma_f32_16x16x32_f16(af, bf1, fa[1][nt], 0, 0, 0);
    }
  }
#pragma unroll
  for (int g = 0; g < 2; ++g) {
    int row = rbase + g * 16 + lm;
    float fs = fscale[row & (SS - 1)];
#pragma unroll
    for (int nt = 0; nt < 2; ++nt) {
      int n = nc0 + nt * 16 + lg * 4;
      float4 bv = *(const float4*)(b1 + n);
      const float* bp = &bv.x;
#pragma unroll
      for (int e = 0; e < 4; ++e) {
        float hf = fs * (fa[g][nt][e] + bp[e]);
        float u = 0.7978845608028654f * hf * (1.0f + 0.044715f * hf * hf);
        float ex = __builtin_amdgcn_exp2f(u * 2.8853900817779268f);  // exp(2u)
        float t = 1.0f - 2.0f / (ex + 1.0f);
        o[g][nt][e] += 0.5f * hf * (1.0f + t);
      }
      *(f32x4*)(out + (size_t)row * HH + n) = o[g][nt];
    }
  }
}

extern "C" void kernel_launch(void* const* d_in, const int* in_sizes, int n_in,
                              void* d_out, int out_size, void* d_ws, size_t ws_size,
                              hipStream_t stream) {
  const float* hidden = (const float*)d_in[0];
  const int* mask = (const int*)d_in[1];
  const float* scalew = (const float*)d_in[2];
  const float* Wl = (const float*)d_in[3];
  const float* bl = (const float*)d_in[4];
  const float* W1 = (const float*)d_in[5];
  const float* b1 = (const float*)d_in[6];
  const float* fscale = (const float*)d_in[7];
  const float* ln1a = (const float*)d_in[8];
  const float* ln1b = (const float*)d_in[9];
  const float* ln2a = (const float*)d_in[10];
  const float* ln2b = (const float*)d_in[11];
  float* out = (float*)d_out;

  const size_t NE = (size_t)BB * SS * HH;  // 2M elements
  f16* n1 = (f16*)d_ws;
  f16* hattf = n1 + NE;
  f16* pnum = hattf + NE;          // 2*NE f16 = 8MB
  f16* Wlf = pnum + 2 * NE;
  f16* W1f = Wlf + HH * HH;
  float* pden = (float*)(W1f + HH * HH);  // 2*B*S f32 = 128KB
  int* idx = (int*)(pden + 2 * BB * SS);
  int* nkcnt = idx + BB * SS;
  int* nkpad = nkcnt + BB;

  stage1_kernel<<<1064, 256, 0, stream>>>(hidden, ln1a, ln1b, Wl, W1, mask,
                                          n1, Wlf, W1f, idx, nkcnt, nkpad);
  attn_kernel<<<2 * BB * NHH * (SS / 128), 256, 0, stream>>>(n1, idx, nkcnt, nkpad,
                                                             scalew, pnum, pden);
  combine_kernel<<<1024, 256, 0, stream>>>(pnum, pden, hattf);
  mlp_kernel<<<BB * SS / 32, 256, 0, stream>>>(hattf, Wlf, bl, hidden, ln2a, ln2b,
                                               W1f, b1, fscale, out);
}

// Round 19
// 39.293 us; speedup vs baseline: 1.0929x; 1.0929x over previous
//
#include <hip/hip_runtime.h>

#define BB 8
#define SS 2048
#define HH 128
#define NHH 4
#define DHH 32

typedef _Float16 f16;
typedef f16 f16x4 __attribute__((ext_vector_type(4)));
typedef f16 f16x8 __attribute__((ext_vector_type(8)));
typedef float f32x4 __attribute__((ext_vector_type(4)));

__device__ __forceinline__ f16x8 cat(f16x4 a, f16x4 b) {
  return (f16x8){a[0], a[1], a[2], a[3], b[0], b[1], b[2], b[3]};
}

// hardware transpose read (R2/R3/R5-proven): on a contiguous [16 rows][16 cols]
// f16 panel, tr_read(panel + lane*4) gives lane(lg,lm) elem j = panel[4*lg+j][lm].
// CALLER MUST wait lgkmcnt(0) + sched_barrier(0) before use (rule #18).
__device__ __forceinline__ f16x4 tr_read(const f16* p) {
  f16x4 d;
  asm volatile("ds_read_b64_tr_b16 %0, %1"
               : "=v"(d)
               : "v"((__attribute__((address_space(3))) const f16*)p)
               : "memory");
  return d;
}

// ---- stage1: LN1 (blocks 0..1023) + weights->f16 (1024..1055) + mask scan (1056..1063)
__global__ __launch_bounds__(256) void stage1_kernel(const float* __restrict__ x,
                                                     const float* __restrict__ ga,
                                                     const float* __restrict__ gb,
                                                     const float* __restrict__ Wl,
                                                     const float* __restrict__ W1,
                                                     const int* __restrict__ mask,
                                                     f16* __restrict__ n1,
                                                     f16* __restrict__ Wlf,
                                                     f16* __restrict__ W1f,
                                                     int* __restrict__ idx,
                                                     int* __restrict__ nkcnt,
                                                     int* __restrict__ nkpad) {
  const int tid = threadIdx.x;
  if (blockIdx.x < 1024) {  // ---- LayerNorm path: 16 rows/block
    const int wave = tid >> 6, lane = tid & 63;
    const int grp = lane >> 4, lm = lane & 15;
    const int r = wave * 4 + grp;
    const size_t row = (size_t)blockIdx.x * 16 + r;

    const float* xr = x + row * HH + lm * 8;
    float4 v0 = *(const float4*)(xr);
    float4 v1 = *(const float4*)(xr + 4);
    float xv[8] = {v0.x, v0.y, v0.z, v0.w, v1.x, v1.y, v1.z, v1.w};
    float sum = 0.f, sq = 0.f;
#pragma unroll
    for (int j = 0; j < 8; ++j) { sum += xv[j]; sq += xv[j] * xv[j]; }
#pragma unroll
    for (int m = 1; m < 16; m <<= 1) {
      sum += __shfl_xor(sum, m);
      sq += __shfl_xor(sq, m);
    }
    float mean = sum * (1.0f / HH);
    float var = fmaxf((sq - (float)HH * mean * mean) * (1.0f / (HH - 1)), 0.0f);
    float inv = 1.0f / (sqrtf(var) + 1e-6f);

    float4 a0 = *(const float4*)(ga + lm * 8);
    float4 a1 = *(const float4*)(ga + lm * 8 + 4);
    float4 b0 = *(const float4*)(gb + lm * 8);
    float4 b1 = *(const float4*)(gb + lm * 8 + 4);
    float av[8] = {a0.x, a0.y, a0.z, a0.w, a1.x, a1.y, a1.z, a1.w};
    float bv[8] = {b0.x, b0.y, b0.z, b0.w, b1.x, b1.y, b1.z, b1.w};
    f16x8 w;
#pragma unroll
    for (int j = 0; j < 8; ++j) w[j] = (f16)(av[j] * (xv[j] - mean) * inv + bv[j]);
    *(f16x8*)(n1 + row * HH + lm * 8) = w;
    return;
  }
  if (blockIdx.x < 1056) {  // ---- weight conversion path
    int g = (blockIdx.x - 1024) * 256 + tid;
    if (g < 4096) {
      float4 w = ((const float4*)Wl)[g];
      f16x4 o = {(f16)w.x, (f16)w.y, (f16)w.z, (f16)w.w};
      ((f16x4*)Wlf)[g] = o;
    } else {
      float4 w = ((const float4*)W1)[g - 4096];
      f16x4 o = {(f16)w.x, (f16)w.y, (f16)w.z, (f16)w.w};
      ((f16x4*)W1f)[g - 4096] = o;
    }
    return;
  }
  // ---- mask scan path: one block per batch
  const int b = blockIdx.x - 1056;
  __shared__ int ps[256];
  int m8[8];
  int cnt = 0;
  const int* mp = mask + b * SS + tid * 8;
#pragma unroll
  for (int j = 0; j < 8; ++j) {
    m8[j] = mp[j];
    cnt += (m8[j] != 0);
  }
  ps[tid] = cnt;
  __syncthreads();
  for (int off = 1; off < 256; off <<= 1) {
    int v = (tid >= off) ? ps[tid - off] : 0;
    __syncthreads();
    ps[tid] += v;
    __syncthreads();
  }
  int pos = ps[tid] - cnt;  // exclusive prefix
#pragma unroll
  for (int j = 0; j < 8; ++j) {
    if (m8[j] != 0) idx[b * SS + pos++] = tid * 8 + j;
  }
  __syncthreads();
  int nkv = ps[255];
  int npv = (nkv + 63) & ~63;
  if (npv == 0) npv = 64;
  for (int jj = nkv + tid; jj < npv; jj += 256) idx[b * SS + jj] = 0;  // safe pad rows
  if (tid == 255) { nkcnt[b] = nkv; nkpad[b] = npv; }
}

// ---- attention: ZERO main-loop-barrier kernel + XCD swizzle:
// b = blockIdx.x & 7 so all blocks of batch b land on XCD b (HW round-robin)
// -> per-XCD L2 working set = n1[b] (512KB) + hattf[b] (512KB) << 4MB L2.
// Wave-private double-buffered tiles; per-wave in-order DS replaces barriers.
// grid = B*NH*(S/128) = 512; 4 waves; wave = 32 q; chunk = 64 keys
__global__ __launch_bounds__(256, 2) void attn_kernel(const f16* __restrict__ n1,
                                                      const int* __restrict__ idx,
                                                      const int* __restrict__ nkcnt,
                                                      const int* __restrict__ nkpad,
                                                      const float* __restrict__ scalew,
                                                      f16* __restrict__ hatt) {
  const int tid = threadIdx.x;
  const int b = blockIdx.x & 7;          // XCD-aligned batch (8 batches <-> 8 XCDs)
  const int qb = (blockIdx.x >> 3) & 15;
  const int h = blockIdx.x >> 7;
  const int wave = tid >> 6, lane = tid & 63;
  const int lg = lane >> 4, lm = lane & 15;
  const int nk = nkcnt[b];
  const int ns = nkpad[b] >> 6;

  __shared__ __align__(16) f16 Kt[4][2][2][64][16];  // [wave][buf][dg][key][16] 32KB
  __shared__ __align__(16) int idxL[SS];             // 8KB

  const f16* __restrict__ nb = n1 + (size_t)b * SS * HH + h * DHH;
  f16* __restrict__ tile = &Kt[wave][0][0][0][0];

  for (int j = tid * 4; j < (ns << 6); j += 1024)
    *(int4*)&idxL[j] = *(const int4*)(idx + b * SS + j);

  const int q0 = qb * 128 + wave * 32 + lm;
  f16x8 qf[2];
#pragma unroll
  for (int qt = 0; qt < 2; ++qt) {
    int q = q0 + qt * 16;
    f16x8 raw = *(const f16x8*)(nb + (size_t)q * HH + lg * 8);
    f16 s = (f16)(scalew[h * SS + q] * 0.2550680718664f);  // (1/sqrt32)*log2e
#pragma unroll
    for (int j = 0; j < 8; ++j) raw[j] *= s;  // fold scale into Q; bias cancels
    qf[qt] = raw;
  }

  const int sk = lane >> 2, sp = lane & 3;  // 4 lanes per key: 64B contiguous slices

  const f32x4 zero = {0.f, 0.f, 0.f, 0.f};
  f32x4 acc[2][2] = {{zero, zero}, {zero, zero}};  // [qt][dh]
  f32x4 lacc[2] = {zero, zero};
  const f16x8 ones = {(f16)1, (f16)1, (f16)1, (f16)1, (f16)1, (f16)1, (f16)1, (f16)1};

  __syncthreads();  // idxL ready — the only barrier before the epilogue

  // prologue: stage chunk 0 into buf 0 (own tile, rounds i = key groups of 16)
#pragma unroll
  for (int i = 0; i < 4; ++i) {
    int row = idxL[i * 16 + sk];
    f16x8 v = *(const f16x8*)(nb + (size_t)row * HH + sp * 8);
    *(f16x8*)(tile + (sp >> 1) * 1024 + (i * 16 + sk) * 16 + (sp & 1) * 8) = v;
  }

  for (int c = 0; c < ns; ++c) {
    const int bo = (c & 1) * 2048;   // current buffer offset (f16 units)
    const int k0 = c * 64;
    f16x8 kreg[4];
    const bool more = (c + 1 < ns);
    if (more) {  // issue next chunk's gather early (consumed at loop bottom)
#pragma unroll
      for (int i = 0; i < 4; ++i) {
        int row = idxL[k0 + 64 + i * 16 + sk];
        kreg[i] = *(const f16x8*)(nb + (size_t)row * HH + sp * 8);
      }
    }

    // V^T fragments first (tr before kf: in-order DS => kf waits cover tr)
    f16x4 t0a = tr_read(tile + bo + 0 + lane * 4);     // dg0 keys 0-15
    f16x4 t0b = tr_read(tile + bo + 256 + lane * 4);   // dg0 keys 16-31
    f16x4 t0c = tr_read(tile + bo + 512 + lane * 4);
    f16x4 t0d = tr_read(tile + bo + 768 + lane * 4);
    f16x4 t1a = tr_read(tile + bo + 1024 + lane * 4);  // dg1
    f16x4 t1b = tr_read(tile + bo + 1280 + lane * 4);
    f16x4 t1c = tr_read(tile + bo + 1536 + lane * 4);
    f16x4 t1d = tr_read(tile + bo + 1792 + lane * 4);

    f16x8 kf[4];
#pragma unroll
    for (int t = 0; t < 4; ++t)
      kf[t] = *(const f16x8*)(tile + bo + (lg >> 1) * 1024 + (t * 16 + lm) * 16 + (lg & 1) * 8);

    const bool tail = (k0 + 64 > nk);
    f16x8 pf[2][2];
#define PF_LOOP(MASKED)                                                                   \
  _Pragma("unroll") for (int qt = 0; qt < 2; ++qt) {                                      \
    _Pragma("unroll") for (int t = 0; t < 4; ++t) {                                       \
      f32x4 st = __builtin_amdgcn_mfma_f32_16x16x32_f16(kf[t], qf[qt], zero, 0, 0, 0);    \
      _Pragma("unroll") for (int r = 0; r < 4; ++r) {                                     \
        float pe = __builtin_amdgcn_exp2f(st[r]);                                         \
        if (MASKED && (k0 + t * 16 + lg * 4 + r >= nk)) pe = 0.0f;                        \
        pf[qt][t >> 1][(t & 1) * 4 + r] = (f16)pe;                                        \
      }                                                                                   \
    }                                                                                     \
  }
    if (!tail) { PF_LOOP(false) } else { PF_LOOP(true) }
#undef PF_LOOP

    // denominator on matrix pipe
#pragma unroll
    for (int qt = 0; qt < 2; ++qt) {
#pragma unroll
      for (int s = 0; s < 2; ++s)
        lacc[qt] = __builtin_amdgcn_mfma_f32_16x16x32_f16(ones, pf[qt][s], lacc[qt], 0, 0, 0);
    }

    asm volatile("s_waitcnt lgkmcnt(0)" ::: "memory");
    __builtin_amdgcn_sched_barrier(0);

    f16x8 vf;
    vf = cat(t0a, t0b);  // dh0, keys 0-31
#pragma unroll
    for (int qt = 0; qt < 2; ++qt)
      acc[qt][0] = __builtin_amdgcn_mfma_f32_16x16x32_f16(vf, pf[qt][0], acc[qt][0], 0, 0, 0);
    vf = cat(t1a, t1b);  // dh1, keys 0-31
#pragma unroll
    for (int qt = 0; qt < 2; ++qt)
      acc[qt][1] = __builtin_amdgcn_mfma_f32_16x16x32_f16(vf, pf[qt][0], acc[qt][1], 0, 0, 0);
    vf = cat(t0c, t0d);  // dh0, keys 32-63
#pragma unroll
    for (int qt = 0; qt < 2; ++qt)
      acc[qt][0] = __builtin_amdgcn_mfma_f32_16x16x32_f16(vf, pf[qt][1], acc[qt][0], 0, 0, 0);
    vf = cat(t1c, t1d);  // dh1, keys 32-63
#pragma unroll
    for (int qt = 0; qt < 2; ++qt)
      acc[qt][1] = __builtin_amdgcn_mfma_f32_16x16x32_f16(vf, pf[qt][1], acc[qt][1], 0, 0, 0);

    if (more) {  // stage chunk c+1 into other buffer (own tile; in-order DS = safe)
      const int bn = 2048 - (c & 1) * 2048;
#pragma unroll
      for (int i = 0; i < 4; ++i)
        *(f16x8*)(tile + bn + (sp >> 1) * 1024 + (i * 16 + sk) * 16 + (sp & 1) * 8) = kreg[i];
    }
  }

#pragma unroll
  for (int qt = 0; qt < 2; ++qt) {
    float inv = 1.0f / lacc[qt][0];
    int q = q0 + qt * 16;
    f16* op = hatt + (size_t)(b * SS + q) * HH + h * DHH;
    f16x4 o0 = {(f16)(acc[qt][0][0] * inv), (f16)(acc[qt][0][1] * inv),
                (f16)(acc[qt][0][2] * inv), (f16)(acc[qt][0][3] * inv)};
    f16x4 o1 = {(f16)(acc[qt][1][0] * inv), (f16)(acc[qt][1][1] * inv),
                (f16)(acc[qt][1][2] * inv), (f16)(acc[qt][1][3] * inv)};
    *(f16x4*)(op + lg * 4) = o0;
    *(f16x4*)(op + 16 + lg * 4) = o1;
  }
}

// ------- fused MLP: 32 rows/block, 256 thr (4 waves x 32 cols) ---------------
__global__ __launch_bounds__(256) void mlp_kernel(const f16* __restrict__ X,
                                                  const f16* __restrict__ Wlf,
                                                  const float* __restrict__ bl,
                                                  const float* __restrict__ resid,
                                                  const float* __restrict__ ln2a,
                                                  const float* __restrict__ ln2b,
                                                  const f16* __restrict__ W1f,
                                                  const float* __restrict__ b1,
                                                  const float* __restrict__ fscale,
                                                  float* __restrict__ out) {
  const int tid = threadIdx.x;
  const int wave = tid >> 6, lane = tid & 63;
  const int lg = lane >> 4, lm = lane & 15;
  const int rbase = blockIdx.x * 32;
  const int nc0 = wave * 32;

  __shared__ __align__(16) f16 n2t[32][136];
  __shared__ float red[4][32][2];

  f32x4 acc[2][2] = {};
  const f16* xr0 = X + (size_t)(rbase + lm) * HH;
  const f16* xr1 = X + (size_t)(rbase + 16 + lm) * HH;
#pragma unroll
  for (int ks = 0; ks < 4; ++ks) {
    f16x8 bf0 = *(const f16x8*)(xr0 + ks * 32 + lg * 8);
    f16x8 bf1 = *(const f16x8*)(xr1 + ks * 32 + lg * 8);
#pragma unroll
    for (int nt = 0; nt < 2; ++nt) {
      f16x8 af = *(const f16x8*)(Wlf + (size_t)(nc0 + nt * 16 + lm) * HH + ks * 32 + lg * 8);
      acc[0][nt] = __builtin_amdgcn_mfma_f32_16x16x32_f16(af, bf0, acc[0][nt], 0, 0, 0);
      acc[1][nt] = __builtin_amdgcn_mfma_f32_16x16x32_f16(af, bf1, acc[1][nt], 0, 0, 0);
    }
  }
  float sum[2] = {0.f, 0.f}, sq[2] = {0.f, 0.f};
  f32x4 o[2][2];
#pragma unroll
  for (int g = 0; g < 2; ++g) {
    int row = rbase + g * 16 + lm;
#pragma unroll
    for (int nt = 0; nt < 2; ++nt) {
      int n = nc0 + nt * 16 + lg * 4;
      float4 rv = *(const float4*)(resid + (size_t)row * HH + n);
      float4 bv = *(const float4*)(bl + n);
      f32x4 v = acc[g][nt];
      v[0] += rv.x + bv.x; v[1] += rv.y + bv.y;
      v[2] += rv.z + bv.z; v[3] += rv.w + bv.w;
      o[g][nt] = v;
      sum[g] += v[0] + v[1] + v[2] + v[3];
      sq[g] += v[0] * v[0] + v[1] * v[1] + v[2] * v[2] + v[3] * v[3];
    }
    sum[g] += __shfl_xor(sum[g], 16); sum[g] += __shfl_xor(sum[g], 32);
    sq[g] += __shfl_xor(sq[g], 16);  sq[g] += __shfl_xor(sq[g], 32);
  }
  if (lane < 16) {
#pragma unroll
    for (int g = 0; g < 2; ++g) {
      red[wave][g * 16 + lm][0] = sum[g];
      red[wave][g * 16 + lm][1] = sq[g];
    }
  }
  __syncthreads();
#pragma unroll
  for (int g = 0; g < 2; ++g) {
    int lr = g * 16 + lm;
    float ts = red[0][lr][0] + red[1][lr][0] + red[2][lr][0] + red[3][lr][0];
    float tq = red[0][lr][1] + red[1][lr][1] + red[2][lr][1] + red[3][lr][1];
    float mean = ts * (1.0f / HH);
    float var = fmaxf((tq - (float)HH * mean * mean) * (1.0f / (HH - 1)), 0.0f);
    float inv = 1.0f / (sqrtf(var) + 1e-6f);
#pragma unroll
    for (int nt = 0; nt < 2; ++nt) {
      int n = nc0 + nt * 16 + lg * 4;
      float4 av = *(const float4*)(ln2a + n);
      float4 b2 = *(const float4*)(ln2b + n);
      f16x4 w;
      w[0] = (f16)(av.x * (o[g][nt][0] - mean) * inv + b2.x);
      w[1] = (f16)(av.y * (o[g][nt][1] - mean) * inv + b2.y);
      w[2] = (f16)(av.z * (o[g][nt][2] - mean) * inv + b2.z);
      w[3] = (f16)(av.w * (o[g][nt][3] - mean) * inv + b2.w);
      *(f16x4*)(&n2t[lr][n]) = w;
    }
  }
  __syncthreads();

  f32x4 fa[2][2] = {};
#pragma unroll
  for (int ks = 0; ks < 4; ++ks) {
    f16x8 bf0 = *(const f16x8*)(&n2t[lm][ks * 32 + lg * 8]);
    f16x8 bf1 = *(const f16x8*)(&n2t[16 + lm][ks * 32 + lg * 8]);
#pragma unroll
    for (int nt = 0; nt < 2; ++nt) {
      f16x8 af = *(const f16x8*)(W1f + (size_t)(nc0 + nt * 16 + lm) * HH + ks * 32 + lg * 8);
      fa[0][nt] = __builtin_amdgcn_mfma_f32_16x16x32_f16(af, bf0, fa[0][nt], 0, 0, 0);
      fa[1][nt] = __builtin_amdgcn_mfma_f32_16x16x32_f16(af, bf1, fa[1][nt], 0, 0, 0);
    }
  }
#pragma unroll
  for (int g = 0; g < 2; ++g) {
    int row = rbase + g * 16 + lm;
    float fs = fscale[row & (SS - 1)];
#pragma unroll
    for (int nt = 0; nt < 2; ++nt) {
      int n = nc0 + nt * 16 + lg * 4;
      float4 bv = *(const float4*)(b1 + n);
      const float* bp = &bv.x;
#pragma unroll
      for (int e = 0; e < 4; ++e) {
        float hf = fs * (fa[g][nt][e] + bp[e]);
        float u = 0.7978845608028654f * hf * (1.0f + 0.044715f * hf * hf);
        float ex = __builtin_amdgcn_exp2f(u * 2.8853900817779268f);  // exp(2u)
        float t = 1.0f - 2.0f / (ex + 1.0f);
        o[g][nt][e] += 0.5f * hf * (1.0f + t);
      }
      *(f32x4*)(out + (size_t)row * HH + n) = o[g][nt];
    }
  }
}

extern "C" void kernel_launch(void* const* d_in, const int* in_sizes, int n_in,
                              void* d_out, int out_size, void* d_ws, size_t ws_size,
                              hipStream_t stream) {
  const float* hidden = (const float*)d_in[0];
  const int* mask = (const int*)d_in[1];
  const float* scalew = (const float*)d_in[2];
  const float* Wl = (const float*)d_in[3];
  const float* bl = (const float*)d_in[4];
  const float* W1 = (const float*)d_in[5];
  const float* b1 = (const float*)d_in[6];
  const float* fscale = (const float*)d_in[7];
  const float* ln1a = (const float*)d_in[8];
  const float* ln1b = (const float*)d_in[9];
  const float* ln2a = (const float*)d_in[10];
  const float* ln2b = (const float*)d_in[11];
  float* out = (float*)d_out;

  const size_t NE = (size_t)BB * SS * HH;  // 2M elements
  f16* n1 = (f16*)d_ws;
  f16* hattf = n1 + NE;
  f16* Wlf = hattf + NE;
  f16* W1f = Wlf + HH * HH;
  int* idx = (int*)(W1f + HH * HH);
  int* nkcnt = idx + BB * SS;
  int* nkpad = nkcnt + BB;

  stage1_kernel<<<1064, 256, 0, stream>>>(hidden, ln1a, ln1b, Wl, W1, mask,
                                          n1, Wlf, W1f, idx, nkcnt, nkpad);
  attn_kernel<<<BB * NHH * (SS / 128), 256, 0, stream>>>(n1, idx, nkcnt, nkpad,
                                                         scalew, hattf);
  mlp_kernel<<<BB * SS / 32, 256, 0, stream>>>(hattf, Wlf, bl, hidden, ln2a, ln2b,
                                               W1f, b1, fscale, out);
}